// Round 2
// baseline (170.406 us; speedup 1.0000x reference)
//
#include <hip/hip_runtime.h>

// ControlFieldModule (all fp32 I/O):
//   fiber = H @ Wf + bf                         [32768, 32]
//   h     = gelu([H|fiber] @ W1 + b1)           [32768, 64]
//   delta = clip(softplus(h @ w2 + b2), 0, 1)   [32768]
//   field = EMA(delta, 0.9) clip [0,10]; gate = sigmoid(-field)
// Fusion: h = gelu(H @ (W1h + Wf@W1f) + (b1 + bf@W1f)) -> one GEMM, N=96.
// EMA == 256-tap causal FIR (0.9^256 ~ 2e-12 << fp32 noise).

#define NTOK  32768   // 8 * 4096
#define SEQ   4096
#define DM    512
#define NC    96      // 32 fiber cols + 64 control cols
#define TB    64      // tokens per block (main kernel)
#define KC    64      // K chunk
#define HPAD  68      // lds_h row stride in floats

// ---------------- kernel 1: build Wc = [Wf | W1h + Wf@W1f] and bc ----------
__global__ __launch_bounds__(256)
void prep_kernel(const float* __restrict__ wf,   // [512,32]
                 const float* __restrict__ bfb,  // [32]
                 const float* __restrict__ w1,   // [544,64]
                 const float* __restrict__ b1,   // [64]
                 float* __restrict__ Wc,         // [512,96]
                 float* __restrict__ bc)         // [96]
{
    int idx = blockIdx.x * 256 + threadIdx.x;
    if (idx < DM * NC) {
        int k = idx / NC, n = idx % NC;
        float v;
        if (n < 32) {
            v = wf[k * 32 + n];
        } else {
            int c = n - 32;
            float a = w1[k * 64 + c];
            for (int f = 0; f < 32; ++f)
                a = fmaf(wf[k * 32 + f], w1[(512 + f) * 64 + c], a);
            v = a;
        }
        Wc[idx] = v;
    }
    if (idx < NC) {
        float v;
        if (idx < 32) {
            v = bfb[idx];
        } else {
            int c = idx - 32;
            float a = b1[c];
            for (int f = 0; f < 32; ++f)
                a = fmaf(bfb[f], w1[(512 + f) * 64 + c], a);
            v = a;
        }
        bc[idx] = v;
    }
}

// ---------------- kernel 2: fused GEMM (N=96) + gelu + softplus epilogue ----
// block = 192 threads: tc = tid%24 (4 cols each), tr = tid/24 (8 tokens each)
__global__ __launch_bounds__(192)
void fused_gemm_kernel(const float* __restrict__ hidden,   // [NTOK,512]
                       const float* __restrict__ Wc,       // [512,96]
                       const float* __restrict__ bc,       // [96]
                       const float* __restrict__ w2,       // [64]
                       const float* __restrict__ b2,       // [1]
                       float* __restrict__ out_delta,      // [NTOK]
                       float* __restrict__ out_fiber)      // [NTOK,32]
{
    __shared__ float lds_h[TB][HPAD];      // 64*68*4  = 17408 B
    __shared__ float lds_w[KC * NC];       // 64*96*4  = 24576 B
    __shared__ float lds_p[TB][25];        // 64*25*4  =  6400 B

    const int tid = threadIdx.x;
    const int tc = tid % 24;
    const int tr = tid / 24;
    const int tok0 = blockIdx.x * TB;

    float acc[8][4];
#pragma unroll
    for (int i = 0; i < 8; ++i)
#pragma unroll
        for (int j = 0; j < 4; ++j) acc[i][j] = 0.f;

    for (int kc = 0; kc < DM; kc += KC) {
        // stage hidden chunk: 64 tokens x 64 k, float4 loads
        for (int v = tid; v < TB * KC / 4; v += 192) {
            int row = v >> 4;            // 16 float4 per row of 64
            int c4  = (v & 15) * 4;
            const float4 u = *(const float4*)(hidden + (size_t)(tok0 + row) * DM + kc + c4);
            *(float4*)&lds_h[row][c4] = u;
        }
        // stage weight chunk (contiguous fp32 rows)
        {
            const float4* wsrc = (const float4*)(Wc + kc * NC);
            float4* wdst = (float4*)lds_w;
            for (int v = tid; v < KC * NC / 4; v += 192) wdst[v] = wsrc[v];
        }
        __syncthreads();

        for (int k4 = 0; k4 < KC; k4 += 4) {
            float4 h4[8];
#pragma unroll
            for (int i = 0; i < 8; ++i)
                h4[i] = *(const float4*)&lds_h[tr + 8 * i][k4];
#pragma unroll
            for (int kk = 0; kk < 4; ++kk) {
                float4 wv = *(const float4*)&lds_w[(k4 + kk) * NC + tc * 4];
#pragma unroll
                for (int i = 0; i < 8; ++i) {
                    float hv = (kk == 0) ? h4[i].x : (kk == 1) ? h4[i].y
                             : (kk == 2) ? h4[i].z : h4[i].w;
                    acc[i][0] = fmaf(hv, wv.x, acc[i][0]);
                    acc[i][1] = fmaf(hv, wv.y, acc[i][1]);
                    acc[i][2] = fmaf(hv, wv.z, acc[i][2]);
                    acc[i][3] = fmaf(hv, wv.w, acc[i][3]);
                }
            }
        }
        __syncthreads();
    }

    // ---- epilogue ----
    const int colbase = tc * 4;
    float bias[4], w2f[4];
#pragma unroll
    for (int j = 0; j < 4; ++j) {
        bias[j] = bc[colbase + j];
        w2f[j] = (colbase >= 32) ? w2[colbase - 32 + j] : 0.f;
    }

    float part[8];
    if (colbase < 32) {
        // fiber output cols
#pragma unroll
        for (int i = 0; i < 8; ++i) {
            int tok = tok0 + tr + 8 * i;
            float4 o;
            o.x = acc[i][0] + bias[0];
            o.y = acc[i][1] + bias[1];
            o.z = acc[i][2] + bias[2];
            o.w = acc[i][3] + bias[3];
            *(float4*)&out_fiber[(size_t)tok * 32 + colbase] = o;
            part[i] = 0.f;
        }
    } else {
        // control cols: exact gelu, partial dot with w2
#pragma unroll
        for (int i = 0; i < 8; ++i) {
            float p = 0.f;
#pragma unroll
            for (int j = 0; j < 4; ++j) {
                float x = acc[i][j] + bias[j];
                float g = 0.5f * x * (1.f + erff(x * 0.70710678118f));
                p = fmaf(g, w2f[j], p);
            }
            part[i] = p;
        }
    }
#pragma unroll
    for (int i = 0; i < 8; ++i) lds_p[tr + 8 * i][tc] = part[i];
    __syncthreads();

    if (tid < TB) {
        float s = b2[0];
#pragma unroll
        for (int t2 = 0; t2 < 24; ++t2) s += lds_p[tid][t2];
        // softplus, numerically safe
        float d = (s > 0.f) ? s + log1pf(expf(-s)) : log1pf(expf(s));
        d = fminf(fmaxf(d, 0.f), 1.f);
        out_delta[tok0 + tid] = d;
    }
}

// ---------------- kernel 3: EMA as 256-tap causal FIR + gate ----------------
__global__ __launch_bounds__(256)
void scan_kernel(const float* __restrict__ delta,   // [8,4096]
                 const float* __restrict__ lam,     // scalar
                 float* __restrict__ out_gate,      // [NTOK]
                 float* __restrict__ out_field)     // [NTOK]
{
    __shared__ float lds_d[512];
    const int b     = blockIdx.x >> 4;   // batch row
    const int chunk = blockIdx.x & 15;   // 256-token chunk within row
    const int s0    = chunk * 256;
    const int tid   = threadIdx.x;

    for (int v = tid; v < 512; v += 256) {
        int s = s0 - 256 + v;
        lds_d[v] = (s >= 0) ? delta[b * SEQ + s] : 0.f;
    }
    __syncthreads();

    float w = 0.1f, acc = 0.f;
    const int base = 256 + tid;
    for (int j = 0; j < 256; ++j) {
        acc = fmaf(w, lds_d[base - j], acc);
        w *= 0.9f;
    }
    float field = fminf(fmaxf(acc, 0.f), 10.f);

    float lamf = lam[0];
    float gate = 1.f / (1.f + expf(lamf * field));
    int t = b * SEQ + s0 + tid;
    out_field[t] = field;
    out_gate[t]  = gate;
}

// ---------------- launcher ----------------
extern "C" void kernel_launch(void* const* d_in, const int* in_sizes, int n_in,
                              void* d_out, int out_size, void* d_ws, size_t ws_size,
                              hipStream_t stream)
{
    const float* hidden = (const float*)d_in[0];
    const float* wf     = (const float*)d_in[1];
    const float* bfb    = (const float*)d_in[2];
    const float* w1     = (const float*)d_in[3];
    const float* b1     = (const float*)d_in[4];
    const float* w2     = (const float*)d_in[5];
    const float* b2     = (const float*)d_in[6];
    const float* lam    = (const float*)d_in[7];
    float* out = (float*)d_out;
    // out layout: gate[32768] | field[32768] | delta[32768] | fiber[32768*32]
    float* out_gate  = out;
    float* out_field = out + NTOK;
    float* out_delta = out + 2 * NTOK;
    float* out_fiber = out + 3 * NTOK;

    float* Wc = (float*)d_ws;                          // 512*96*4 = 196608 B
    float* bc = (float*)((char*)d_ws + DM * NC * 4);   // 384 B

    hipLaunchKernelGGL(prep_kernel, dim3(192), dim3(256), 0, stream,
                       wf, bfb, w1, b1, Wc, bc);
    hipLaunchKernelGGL(fused_gemm_kernel, dim3(NTOK / TB), dim3(192), 0, stream,
                       hidden, Wc, bc, w2, b2, out_delta, out_fiber);
    hipLaunchKernelGGL(scan_kernel, dim3(128), dim3(256), 0, stream,
                       out_delta, lam, out_gate, out_field);
}

// Round 3
// 116.059 us; speedup vs baseline: 1.4683x; 1.4683x over previous
//
#include <hip/hip_runtime.h>
#include <hip/hip_bf16.h>

// ControlFieldModule (fp32 I/O), MFMA-bf16 GEMM version.
//   fiber = H @ Wf + bf                         [32768, 32]
//   h     = gelu([H|fiber] @ W1 + b1)           [32768, 64]
//   delta = clip(softplus(h @ w2 + b2), 0, 1)   [32768]
//   field = EMA(delta, 0.9) clip [0,10]; gate = sigmoid(-field)
// Fusion: one GEMM C[32768,96] = H @ [Wf | W1h + Wf@W1f] (bias folded),
// computed with v_mfma_f32_16x16x32_bf16 (inputs rounded to bf16; threshold
// 0.11 >> expected ~3e-2 error). EMA == 256-tap causal FIR (0.9^256 ~ 2e-12).

#define NTOK  32768   // 8 * 4096
#define SEQ   4096
#define DM    512
#define NC    96      // 32 fiber + 64 control cols
#define TB    64      // tokens per block
#define KC    128     // K chunk
#define LROW  136     // padded LDS row stride in bf16 elems (272 B = 68 dw ≡ 4 mod 32 -> 2-way free)

typedef short bf16x8 __attribute__((ext_vector_type(8)));
typedef float f32x4  __attribute__((ext_vector_type(4)));

__device__ __forceinline__ unsigned short f2bf(float f) {
    __hip_bfloat16 h = __float2bfloat16(f);
    return *reinterpret_cast<unsigned short*>(&h);
}

// ---- kernel 1: build Wt = [Wf | W1h + Wf@W1f]^T as bf16 [96][512], bc fp32 [96]
__global__ __launch_bounds__(256)
void prep_kernel(const float* __restrict__ wf,   // [512,32]
                 const float* __restrict__ bfb,  // [32]
                 const float* __restrict__ w1,   // [544,64]
                 const float* __restrict__ b1,   // [64]
                 unsigned short* __restrict__ Wt, // [96,512] bf16
                 float* __restrict__ bc)          // [96]
{
    int idx = blockIdx.x * 256 + threadIdx.x;     // 0 .. 96*512-1
    if (idx < NC * DM) {
        int n = idx >> 9, k = idx & 511;
        float v;
        if (n < 32) {
            v = wf[k * 32 + n];
        } else {
            int c = n - 32;
            v = w1[k * 64 + c];
            for (int f = 0; f < 32; ++f)
                v = fmaf(wf[k * 32 + f], w1[(512 + f) * 64 + c], v);
        }
        Wt[idx] = f2bf(v);
    }
    if (idx < NC) {
        float v;
        if (idx < 32) {
            v = bfb[idx];
        } else {
            int c = idx - 32;
            v = b1[c];
            for (int f = 0; f < 32; ++f)
                v = fmaf(bfb[f], w1[(512 + f) * 64 + c], v);
        }
        bc[idx] = v;
    }
}

// ---- kernel 2: MFMA GEMM (M=64/block, N=96, K=512) + gelu/softplus epilogue
// 256 threads = 4 waves; wave w owns M-tile rows [w*16, w*16+16), all 6 N-tiles.
__global__ __launch_bounds__(256, 2)
void fused_gemm_kernel(const float* __restrict__ hidden,        // [NTOK,512]
                       const unsigned short* __restrict__ Wt,   // [96,512] bf16
                       const float* __restrict__ bc,            // [96]
                       const float* __restrict__ w2,            // [64]
                       const float* __restrict__ b2,            // [1]
                       float* __restrict__ out_delta,           // [NTOK]
                       float* __restrict__ out_fiber)           // [NTOK,32]
{
    __shared__ unsigned short a_lds[TB * LROW];   // 17408 B
    __shared__ unsigned short b_lds[NC * LROW];   // 26112 B

    const int tid  = threadIdx.x;
    const int wave = tid >> 6;
    const int lane = tid & 63;
    const int quad = lane >> 4;
    const int l15  = lane & 15;
    const int tok0 = blockIdx.x * TB;

    f32x4 acc[6];
#pragma unroll
    for (int t = 0; t < 6; ++t) acc[t] = (f32x4){0.f, 0.f, 0.f, 0.f};

    for (int kc = 0; kc < DM; kc += KC) {
        // stage A: 64 tokens x 128 k, fp32 -> bf16 (2048 float4 / 256 thr)
#pragma unroll
        for (int it = 0; it < 8; ++it) {
            int v   = it * 256 + tid;
            int row = v >> 5;             // 32 float4 per row
            int c4  = v & 31;
            float4 u = *(const float4*)(hidden + (size_t)(tok0 + row) * DM + kc + c4 * 4);
            ushort4 o;
            o.x = f2bf(u.x); o.y = f2bf(u.y); o.z = f2bf(u.z); o.w = f2bf(u.w);
            *(ushort4*)&a_lds[row * LROW + c4 * 4] = o;
        }
        // stage B: 96 rows x 128 k bf16 (1536 x 16B / 256 thr)
#pragma unroll
        for (int it = 0; it < 6; ++it) {
            int v   = it * 256 + tid;
            int row = v >> 4;             // 16 x ushort8 per row
            int c8  = v & 15;
            bf16x8 u = *(const bf16x8*)(Wt + row * DM + kc + c8 * 8);
            *(bf16x8*)&b_lds[row * LROW + c8 * 8] = u;
        }
        __syncthreads();

#pragma unroll
        for (int ks = 0; ks < 4; ++ks) {
            bf16x8 af = *(const bf16x8*)&a_lds[(wave * 16 + l15) * LROW + ks * 32 + quad * 8];
#pragma unroll
            for (int t = 0; t < 6; ++t) {
                bf16x8 bfv = *(const bf16x8*)&b_lds[(t * 16 + l15) * LROW + ks * 32 + quad * 8];
                acc[t] = __builtin_amdgcn_mfma_f32_16x16x32_bf16(af, bfv, acc[t], 0, 0, 0);
            }
        }
        __syncthreads();
    }

    // ---- epilogue ----
    // C/D layout: col = lane&15 (within N-tile), row = quad*4 + reg.
    const int mbase = tok0 + wave * 16 + quad * 4;

    // fiber tiles 0,1 -> out_fiber
#pragma unroll
    for (int t = 0; t < 2; ++t) {
        int col = t * 16 + l15;
        float bias = bc[col];
#pragma unroll
        for (int r = 0; r < 4; ++r)
            out_fiber[(size_t)(mbase + r) * 32 + col] = acc[t][r] + bias;
    }

    // control tiles 2..5: gelu(x)*w2, reduce 64 cols -> delta
    float p0 = 0.f, p1 = 0.f, p2 = 0.f, p3 = 0.f;
#pragma unroll
    for (int t = 2; t < 6; ++t) {
        int c = (t - 2) * 16 + l15;
        float bias = bc[32 + c];
        float w2v  = w2[c];
        float x, g;
        x = acc[t][0] + bias; g = 0.5f * x * (1.f + erff(x * 0.70710678118f)); p0 = fmaf(g, w2v, p0);
        x = acc[t][1] + bias; g = 0.5f * x * (1.f + erff(x * 0.70710678118f)); p1 = fmaf(g, w2v, p1);
        x = acc[t][2] + bias; g = 0.5f * x * (1.f + erff(x * 0.70710678118f)); p2 = fmaf(g, w2v, p2);
        x = acc[t][3] + bias; g = 0.5f * x * (1.f + erff(x * 0.70710678118f)); p3 = fmaf(g, w2v, p3);
    }
    // butterfly over the 16 lanes sharing this quad (masks 1,2,4,8 stay in-group)
#pragma unroll
    for (int m = 1; m <= 8; m <<= 1) {
        p0 += __shfl_xor(p0, m);
        p1 += __shfl_xor(p1, m);
        p2 += __shfl_xor(p2, m);
        p3 += __shfl_xor(p3, m);
    }
    if (l15 < 4) {
        float pv = (l15 == 0) ? p0 : (l15 == 1) ? p1 : (l15 == 2) ? p2 : p3;
        float s = pv + b2[0];
        float d = (s > 0.f) ? s + log1pf(expf(-s)) : log1pf(expf(s));
        d = fminf(fmaxf(d, 0.f), 1.f);
        out_delta[mbase + l15] = d;
    }
}

// ---- kernel 3: EMA as 256-tap causal FIR + gate ----
__global__ __launch_bounds__(256)
void scan_kernel(const float* __restrict__ delta,   // [8,4096]
                 const float* __restrict__ lam,     // scalar
                 float* __restrict__ out_gate,      // [NTOK]
                 float* __restrict__ out_field)     // [NTOK]
{
    __shared__ float lds_d[512];
    const int b     = blockIdx.x >> 4;   // batch row
    const int chunk = blockIdx.x & 15;   // 256-token chunk
    const int s0    = chunk * 256;
    const int tid   = threadIdx.x;

    for (int v = tid; v < 512; v += 256) {
        int s = s0 - 256 + v;
        lds_d[v] = (s >= 0) ? delta[b * SEQ + s] : 0.f;
    }
    __syncthreads();

    float w = 0.1f, acc = 0.f;
    const int base = 256 + tid;
    for (int j = 0; j < 256; ++j) {
        acc = fmaf(w, lds_d[base - j], acc);
        w *= 0.9f;
    }
    float field = fminf(fmaxf(acc, 0.f), 10.f);

    float gate = 1.f / (1.f + expf(lam[0] * field));
    int t = b * SEQ + s0 + tid;
    out_field[t] = field;
    out_gate[t]  = gate;
}

// ---- launcher ----
extern "C" void kernel_launch(void* const* d_in, const int* in_sizes, int n_in,
                              void* d_out, int out_size, void* d_ws, size_t ws_size,
                              hipStream_t stream)
{
    const float* hidden = (const float*)d_in[0];
    const float* wf     = (const float*)d_in[1];
    const float* bfb    = (const float*)d_in[2];
    const float* w1     = (const float*)d_in[3];
    const float* b1     = (const float*)d_in[4];
    const float* w2     = (const float*)d_in[5];
    const float* b2     = (const float*)d_in[6];
    const float* lam    = (const float*)d_in[7];
    float* out = (float*)d_out;
    // out layout: gate[32768] | field[32768] | delta[32768] | fiber[32768*32]
    float* out_gate  = out;
    float* out_field = out + NTOK;
    float* out_delta = out + 2 * NTOK;
    float* out_fiber = out + 3 * NTOK;

    unsigned short* Wt = (unsigned short*)d_ws;                 // 96*512*2 = 98304 B
    float* bc          = (float*)((char*)d_ws + NC * DM * 2);   // 384 B

    hipLaunchKernelGGL(prep_kernel, dim3((NC * DM + 255) / 256), dim3(256), 0, stream,
                       wf, bfb, w1, b1, Wt, bc);
    hipLaunchKernelGGL(fused_gemm_kernel, dim3(NTOK / TB), dim3(256), 0, stream,
                       hidden, Wt, bc, w2, b2, out_delta, out_fiber);
    hipLaunchKernelGGL(scan_kernel, dim3(128), dim3(256), 0, stream,
                       out_delta, lam, out_gate, out_field);
}